// Round 3
// baseline (542.649 us; speedup 1.0000x reference)
//
#include <hip/hip_runtime.h>

// VQC: 18 qubits, 4 layers, batch 64.
// state[b][i], i = 18-bit index; qubit q <-> index bit (17-q).
// Layer = 18 one-qubit rotations (commuting) + CNOT chain == Gray permutation:
//   after_perm[o] = rotated[o ^ (o>>1)]   (folded into next phase-A load)
// Phase A: gates on index bits 0..8 (qubits 17..9), wave-local (regs + shfl).
// Phase B: gates on index bits 9..17 (qubits 8..0), LDS-transposed tile, in-place.
// Layer 0 on a basis input = outer product A_b[r]*B[c]; fused into first phase A.
// Final permutation + measurement folded into the last phase B (FINAL=1):
//   index bits 17..14 are lane bits 5..2 there, so signs are per-lane constants.
// State buffers are __device__ globals -> zero assumptions about ws_size.

#define NQ 18
#define STATE_ELEMS ((size_t)1 << 24)  // 64 batches * 2^18

using cplx = float2;

__device__ cplx g_S[2][STATE_ELEMS];   // 2 x 128 MiB ping-pong
__device__ cplx g_Utab[4 * NQ * 4];
__device__ cplx g_Btab[512];

__device__ __forceinline__ cplx cmul(cplx a, cplx b) {
    return make_float2(a.x * b.x - a.y * b.y, a.x * b.y + a.y * b.x);
}
// a*o0 + b*o1 (complex)
__device__ __forceinline__ cplx cfma2(cplx a, cplx o0, cplx b, cplx o1) {
    float re = fmaf(a.x, o0.x, fmaf(-a.y, o0.y, fmaf(b.x, o1.x, -b.y * o1.y)));
    float im = fmaf(a.x, o0.y, fmaf(a.y, o0.x, fmaf(b.x, o1.y, b.y * o1.x)));
    return make_float2(re, im);
}

// ---------------------------------------------------------------- prep ------
// Utab[(l*18+q)*4 + row*2 + col]; Btab[c] = prod_j U[0][9+j][c_bit][0]
__global__ __launch_bounds__(512) void k_prep(const float* __restrict__ w) {
    __shared__ cplx Us[4 * NQ * 4];
    int tid = threadIdx.x;
    if (tid < 4 * NQ) {
        float phi = w[tid * 3 + 0], th = w[tid * 3 + 1], om = w[tid * 3 + 2];
        float s, c, sa, ca, sb, cb;
        sincosf(0.5f * th, &s, &c);
        sincosf(-0.5f * (phi + om), &sa, &ca);   // a = exp(-i(phi+om)/2)
        sincosf(0.5f * (phi - om), &sb, &cb);    // b = exp(+i(phi-om)/2)
        cplx U00 = make_float2(ca * c, sa * c);
        cplx U01 = make_float2(-cb * s, -sb * s);
        cplx U10 = make_float2(cb * s, -sb * s);  // conj(b)*s
        cplx U11 = make_float2(ca * c, -sa * c);  // conj(a)*c
        Us[tid * 4 + 0] = U00; Us[tid * 4 + 1] = U01;
        Us[tid * 4 + 2] = U10; Us[tid * 4 + 3] = U11;
        g_Utab[tid * 4 + 0] = U00; g_Utab[tid * 4 + 1] = U01;
        g_Utab[tid * 4 + 2] = U10; g_Utab[tid * 4 + 3] = U11;
    }
    __syncthreads();
    int c = tid;  // 0..511
    cplx B = make_float2(1.f, 0.f);
#pragma unroll
    for (int j = 0; j < 9; ++j) {
        int bit = (c >> (8 - j)) & 1;               // qubit 9+j = c bit (8-j)
        B = cmul(B, Us[(9 + j) * 4 + bit * 2 + 0]); // input bit 0
    }
    g_Btab[c] = B;
}

// ------------------------------------------------------------- gates --------
__device__ __forceinline__ void gate_inreg(cplx* T, int stride,
                                           cplx U00, cplx U01, cplx U10, cplx U11) {
#pragma unroll
    for (int t = 0; t < 8; ++t) {
        if ((t & stride) == 0) {
            cplx o0 = T[t], o1 = T[t | stride];
            T[t]          = cfma2(U00, o0, U01, o1);
            T[t | stride] = cfma2(U10, o0, U11, o1);
        }
    }
}
__device__ __forceinline__ void gate_shfl(cplx* T, int mask, int lanebit,
                                          cplx U00, cplx U01, cplx U10, cplx U11) {
    cplx ca = lanebit ? U11 : U00;
    cplx cb = lanebit ? U10 : U01;
#pragma unroll
    for (int t = 0; t < 8; ++t) {
        cplx p;
        p.x = __shfl_xor(T[t].x, mask);
        p.y = __shfl_xor(T[t].y, mask);
        T[t] = cfma2(ca, T[t], cb, p);
    }
}

#define GQ(q) UL[(q)*4+0], UL[(q)*4+1], UL[(q)*4+2], UL[(q)*4+3]

// ------------------------------------------------------------ phase A -------
// Per wave: output chunk h (512 elems) of batch b. Loads source chunk
// g = h^(h>>1) with the in-chunk Gray gather (per-lane 64B block, in-register
// unpermute), applies low-bit gates of `layer`, stores contiguous chunk h.
// GEN: source = A_b[g] * Btab[] (layer-0 output on basis state).
template <int GEN>
__global__ __launch_bounds__(256) void k_phaseA(int srcSel, int dstSel,
                                                const int* __restrict__ x,
                                                int layer) {
    const cplx* __restrict__ src = g_S[srcSel];
    cplx* __restrict__ dst = g_S[dstSel];
    const int lane = threadIdx.x & 63;
    const int W = blockIdx.x * 4 + (threadIdx.x >> 6);
    const int b = W >> 9;
    const int h = W & 511;
    const int g = h ^ (h >> 1);
    const int h0 = h & 1;
    const int blk = (lane ^ (lane >> 1)) ^ (h0 << 5);

    const float4* ls;
    if (GEN) ls = (const float4*)(g_Btab + blk * 8);
    else     ls = (const float4*)(src + (((size_t)b << 18) | (size_t)(g << 9)) + blk * 8);
    float4 q0 = ls[0], q1 = ls[1], q2 = ls[2], q3 = ls[3];
    cplx v[8] = { {q0.x,q0.y},{q0.z,q0.w},{q1.x,q1.y},{q1.z,q1.w},
                  {q2.x,q2.y},{q2.z,q2.w},{q3.x,q3.y},{q3.z,q3.w} };
    if (lane & 1) {  // in-block index ^= 4
#pragma unroll
        for (int j = 0; j < 4; ++j) { cplx t = v[j]; v[j] = v[j + 4]; v[j + 4] = t; }
    }
    // T[t] = v[gray3(t)]
    cplx T[8] = { v[0], v[1], v[3], v[2], v[6], v[7], v[5], v[4] };

    if (GEN) {
        cplx A = make_float2(1.f, 0.f);
#pragma unroll
        for (int j = 0; j < 9; ++j) {
            int bit = (g >> (8 - j)) & 1;  // qubit j = g bit (8-j)
            int xb = x[b * 9 + j];
            A = cmul(A, g_Utab[j * 4 + bit * 2 + xb]);
        }
#pragma unroll
        for (int t = 0; t < 8; ++t) T[t] = cmul(T[t], A);
    }

    const cplx* UL = g_Utab + layer * NQ * 4;
    gate_inreg(T, 1, GQ(17));   // index bit 0
    gate_inreg(T, 2, GQ(16));   // index bit 1
    gate_inreg(T, 4, GQ(15));   // index bit 2
    gate_shfl(T, 1,  lane & 1,  GQ(14));  // index bit 3
    gate_shfl(T, 2,  lane & 2,  GQ(13));
    gate_shfl(T, 4,  lane & 4,  GQ(12));
    gate_shfl(T, 8,  lane & 8,  GQ(11));
    gate_shfl(T, 16, lane & 16, GQ(10));
    gate_shfl(T, 32, lane & 32, GQ(9));   // index bit 8

    float4* ld = (float4*)(dst + (((size_t)b << 18) | (size_t)(h << 9)) + lane * 8);
    ld[0] = make_float4(T[0].x, T[0].y, T[1].x, T[1].y);
    ld[1] = make_float4(T[2].x, T[2].y, T[3].x, T[3].y);
    ld[2] = make_float4(T[4].x, T[4].y, T[5].x, T[5].y);
    ld[3] = make_float4(T[6].x, T[6].y, T[7].x, T[7].y);
}

// ------------------------------------------------------------ phase B -------
// In-place. Block: batch b, 8 columns (low-bit values), all 512 rows.
// LDS tile col-major, 16B-unit XOR swizzle (u' = u ^ ((u>>3)&7)) -> even bank
// distribution on all LDS accesses. Wave wv owns column wv: 8 rows/lane.
// FINAL: instead of writing back, fold final Gray perm + measurement:
//   index bits 17..14 = lane bits 5..2 -> signs are per-lane constants.
template <int FINAL>
__global__ __launch_bounds__(512) void k_phaseB(int sel, int layer,
                                                float* __restrict__ out) {
    cplx* __restrict__ state = g_S[sel];
    __shared__ cplx tile[8 * 512];  // 32 KiB
    __shared__ float facc[8][4];
    const int tid = threadIdx.x;
    const int lane = tid & 63;
    const int wv = tid >> 6;                 // 0..7
    const int b = blockIdx.x >> 6;
    const int cb = blockIdx.x & 63;          // column block (8 cols)
    cplx* gbase = state + (((size_t)b << 18) | (size_t)(cb * 8));

    {   // stage in: thread tid = row r, 8 cols = 64B contiguous
        const int r = tid;
        const float4* gs = (const float4*)(gbase + ((size_t)r << 9));
        float4 a0 = gs[0], a1 = gs[1], a2 = gs[2], a3 = gs[3];
        cplx wv8[8] = { {a0.x,a0.y},{a0.z,a0.w},{a1.x,a1.y},{a1.z,a1.w},
                        {a2.x,a2.y},{a2.z,a2.w},{a3.x,a3.y},{a3.z,a3.w} };
        int u = r >> 1;
        int us = u ^ ((u >> 3) & 7);
        int basep = us * 2 + (r & 1);
#pragma unroll
        for (int k = 0; k < 8; ++k) tile[k * 512 + basep] = wv8[k];
    }
    __syncthreads();

    cplx T[8];  // rows lane*8 .. lane*8+7 of column wv
#pragma unroll
    for (int j = 0; j < 4; ++j) {
        int u = lane * 4 + j;
        int us = u ^ ((u >> 3) & 7);
        float4 q = *(const float4*)&tile[wv * 512 + us * 2];
        T[2 * j]     = make_float2(q.x, q.y);
        T[2 * j + 1] = make_float2(q.z, q.w);
    }

    const cplx* UL = g_Utab + layer * NQ * 4;
    gate_inreg(T, 1, GQ(8));    // index bit 9
    gate_inreg(T, 2, GQ(7));
    gate_inreg(T, 4, GQ(6));
    gate_shfl(T, 1,  lane & 1,  GQ(5));  // index bit 12
    gate_shfl(T, 2,  lane & 2,  GQ(4));
    gate_shfl(T, 4,  lane & 4,  GQ(3));
    gate_shfl(T, 8,  lane & 8,  GQ(2));
    gate_shfl(T, 16, lane & 16, GQ(1));
    gate_shfl(T, 32, lane & 32, GQ(0));  // index bit 17

    if (FINAL) {
        float s = 0.f;
#pragma unroll
        for (int t = 0; t < 8; ++t)
            s = fmaf(T[t].x, T[t].x, fmaf(T[t].y, T[t].y, s));
        // final perm: o = invGray(m); sign bits = prefix parity of m bits 17..14
        int l5 = (lane >> 5) & 1, l4 = (lane >> 4) & 1;
        int l3 = (lane >> 3) & 1, l2 = (lane >> 2) & 1;
        int o17 = l5, o16 = o17 ^ l4, o15 = o16 ^ l3, o14 = o15 ^ l2;
        float e0 = o17 ? -s : s, e1 = o16 ? -s : s;
        float e2 = o15 ? -s : s, e3 = o14 ? -s : s;
#pragma unroll
        for (int off = 32; off >= 1; off >>= 1) {
            e0 += __shfl_xor(e0, off); e1 += __shfl_xor(e1, off);
            e2 += __shfl_xor(e2, off); e3 += __shfl_xor(e3, off);
        }
        if (lane == 0) {
            facc[wv][0] = e0; facc[wv][1] = e1;
            facc[wv][2] = e2; facc[wv][3] = e3;
        }
        __syncthreads();
        if (tid < 4) {
            float tot = 0.f;
#pragma unroll
            for (int k = 0; k < 8; ++k) tot += facc[k][tid];
            atomicAdd(&out[b * 4 + tid], tot);
        }
        return;
    }

#pragma unroll
    for (int j = 0; j < 4; ++j) {   // write back own column (no cross-wave hazard)
        int u = lane * 4 + j;
        int us = u ^ ((u >> 3) & 7);
        *(float4*)&tile[wv * 512 + us * 2] =
            make_float4(T[2 * j].x, T[2 * j].y, T[2 * j + 1].x, T[2 * j + 1].y);
    }
    __syncthreads();

    {   // stage out
        const int r = tid;
        int u = r >> 1;
        int us = u ^ ((u >> 3) & 7);
        int basep = us * 2 + (r & 1);
        cplx o[8];
#pragma unroll
        for (int k = 0; k < 8; ++k) o[k] = tile[k * 512 + basep];
        float4* gd = (float4*)(gbase + ((size_t)r << 9));
        gd[0] = make_float4(o[0].x, o[0].y, o[1].x, o[1].y);
        gd[1] = make_float4(o[2].x, o[2].y, o[3].x, o[3].y);
        gd[2] = make_float4(o[4].x, o[4].y, o[5].x, o[5].y);
        gd[3] = make_float4(o[6].x, o[6].y, o[7].x, o[7].y);
    }
}

// ------------------------------------------------------------- launch -------
extern "C" void kernel_launch(void* const* d_in, const int* in_sizes, int n_in,
                              void* d_out, int out_size, void* d_ws, size_t ws_size,
                              hipStream_t stream) {
    const float* w = (const float*)d_in[0];   // (4,18,3) f32
    const int* x = (const int*)d_in[1];       // (64,9) i32
    float* out = (float*)d_out;               // (64,4) f32
    (void)d_ws; (void)ws_size; (void)n_in; (void)in_sizes;

    hipMemsetAsync(d_out, 0, (size_t)out_size * sizeof(float), stream);
    k_prep<<<1, 512, 0, stream>>>(w);
    // layer 0 (A*B outer product) + perm + layer-1 low gates -> S0
    k_phaseA<1><<<8192, 256, 0, stream>>>(0, 0, x, 1);
    k_phaseB<0><<<4096, 512, 0, stream>>>(0, 1, nullptr);   // layer-1 high gates
    k_phaseA<0><<<8192, 256, 0, stream>>>(0, 1, x, 2);
    k_phaseB<0><<<4096, 512, 0, stream>>>(1, 2, nullptr);
    k_phaseA<0><<<8192, 256, 0, stream>>>(1, 0, x, 3);
    // layer-3 high gates + final perm + measurement (no writeback)
    k_phaseB<1><<<4096, 512, 0, stream>>>(0, 3, out);
}

// Round 4
// 430.511 us; speedup vs baseline: 1.2605x; 1.2605x over previous
//
#include <hip/hip_runtime.h>

// VQC: 18 qubits, 4 layers, batch 64.
// state[b][i], i = 18-bit index; qubit q <-> index bit (17-q).
// Layer = 18 one-qubit rotations (commuting) + CNOT chain == Gray permutation:
//   after_perm[o] = rotated[o ^ (o>>1)]   (folded into next phase-A load)
// Phase A: gates on index bits 0..8 (qubits 17..9), wave-local (regs + shfl).
// Phase B: gates on index bits 9..17 (qubits 8..0), LDS-transposed tile, in-place.
//   R3 fix: 16 cols/block (128 B per row = full cache lines; was 8 cols/64 B,
//   which over-fetched 1.47x). 1024 threads: tid pair covers one line.
// Layer 0 on a basis input = outer product A_b[r]*B[c]; fused into first phase A.
// Final permutation + measurement folded into the last phase B (FINAL=1).
// State buffers are __device__ globals -> zero assumptions about ws_size.

#define NQ 18
#define STATE_ELEMS ((size_t)1 << 24)  // 64 batches * 2^18

using cplx = float2;

__device__ cplx g_S[2][STATE_ELEMS];   // 2 x 128 MiB ping-pong
__device__ cplx g_Utab[4 * NQ * 4];
__device__ cplx g_Btab[512];

__device__ __forceinline__ cplx cmul(cplx a, cplx b) {
    return make_float2(a.x * b.x - a.y * b.y, a.x * b.y + a.y * b.x);
}
// a*o0 + b*o1 (complex)
__device__ __forceinline__ cplx cfma2(cplx a, cplx o0, cplx b, cplx o1) {
    float re = fmaf(a.x, o0.x, fmaf(-a.y, o0.y, fmaf(b.x, o1.x, -b.y * o1.y)));
    float im = fmaf(a.x, o0.y, fmaf(a.y, o0.x, fmaf(b.x, o1.y, b.y * o1.x)));
    return make_float2(re, im);
}

// ---------------------------------------------------------------- prep ------
// Utab[(l*18+q)*4 + row*2 + col]; Btab[c] = prod_j U[0][9+j][c_bit][0]
__global__ __launch_bounds__(512) void k_prep(const float* __restrict__ w) {
    __shared__ cplx Us[4 * NQ * 4];
    int tid = threadIdx.x;
    if (tid < 4 * NQ) {
        float phi = w[tid * 3 + 0], th = w[tid * 3 + 1], om = w[tid * 3 + 2];
        float s, c, sa, ca, sb, cb;
        sincosf(0.5f * th, &s, &c);
        sincosf(-0.5f * (phi + om), &sa, &ca);   // a = exp(-i(phi+om)/2)
        sincosf(0.5f * (phi - om), &sb, &cb);    // b = exp(+i(phi-om)/2)
        cplx U00 = make_float2(ca * c, sa * c);
        cplx U01 = make_float2(-cb * s, -sb * s);
        cplx U10 = make_float2(cb * s, -sb * s);  // conj(b)*s
        cplx U11 = make_float2(ca * c, -sa * c);  // conj(a)*c
        Us[tid * 4 + 0] = U00; Us[tid * 4 + 1] = U01;
        Us[tid * 4 + 2] = U10; Us[tid * 4 + 3] = U11;
        g_Utab[tid * 4 + 0] = U00; g_Utab[tid * 4 + 1] = U01;
        g_Utab[tid * 4 + 2] = U10; g_Utab[tid * 4 + 3] = U11;
    }
    __syncthreads();
    int c = tid;  // 0..511
    cplx B = make_float2(1.f, 0.f);
#pragma unroll
    for (int j = 0; j < 9; ++j) {
        int bit = (c >> (8 - j)) & 1;               // qubit 9+j = c bit (8-j)
        B = cmul(B, Us[(9 + j) * 4 + bit * 2 + 0]); // input bit 0
    }
    g_Btab[c] = B;
}

// ------------------------------------------------------------- gates --------
__device__ __forceinline__ void gate_inreg(cplx* T, int stride,
                                           cplx U00, cplx U01, cplx U10, cplx U11) {
#pragma unroll
    for (int t = 0; t < 8; ++t) {
        if ((t & stride) == 0) {
            cplx o0 = T[t], o1 = T[t | stride];
            T[t]          = cfma2(U00, o0, U01, o1);
            T[t | stride] = cfma2(U10, o0, U11, o1);
        }
    }
}
__device__ __forceinline__ void gate_shfl(cplx* T, int mask, int lanebit,
                                          cplx U00, cplx U01, cplx U10, cplx U11) {
    cplx ca = lanebit ? U11 : U00;
    cplx cb = lanebit ? U10 : U01;
#pragma unroll
    for (int t = 0; t < 8; ++t) {
        cplx p;
        p.x = __shfl_xor(T[t].x, mask);
        p.y = __shfl_xor(T[t].y, mask);
        T[t] = cfma2(ca, T[t], cb, p);
    }
}

#define GQ(q) UL[(q)*4+0], UL[(q)*4+1], UL[(q)*4+2], UL[(q)*4+3]

// ------------------------------------------------------------ phase A -------
// Per wave: output chunk h (512 elems) of batch b. Loads source chunk
// g = h^(h>>1) with the in-chunk Gray gather (per-lane 64B block, in-register
// unpermute), applies low-bit gates of `layer`, stores contiguous chunk h.
// GEN: source = A_b[g] * Btab[] (layer-0 output on basis state).
template <int GEN>
__global__ __launch_bounds__(256) void k_phaseA(int srcSel, int dstSel,
                                                const int* __restrict__ x,
                                                int layer) {
    const cplx* __restrict__ src = g_S[srcSel];
    cplx* __restrict__ dst = g_S[dstSel];
    const int lane = threadIdx.x & 63;
    const int W = blockIdx.x * 4 + (threadIdx.x >> 6);
    const int b = W >> 9;
    const int h = W & 511;
    const int g = h ^ (h >> 1);
    const int h0 = h & 1;
    const int blk = (lane ^ (lane >> 1)) ^ (h0 << 5);

    const float4* ls;
    if (GEN) ls = (const float4*)(g_Btab + blk * 8);
    else     ls = (const float4*)(src + (((size_t)b << 18) | (size_t)(g << 9)) + blk * 8);
    float4 q0 = ls[0], q1 = ls[1], q2 = ls[2], q3 = ls[3];
    cplx v[8] = { {q0.x,q0.y},{q0.z,q0.w},{q1.x,q1.y},{q1.z,q1.w},
                  {q2.x,q2.y},{q2.z,q2.w},{q3.x,q3.y},{q3.z,q3.w} };
    if (lane & 1) {  // in-block index ^= 4
#pragma unroll
        for (int j = 0; j < 4; ++j) { cplx t = v[j]; v[j] = v[j + 4]; v[j + 4] = t; }
    }
    // T[t] = v[gray3(t)]
    cplx T[8] = { v[0], v[1], v[3], v[2], v[6], v[7], v[5], v[4] };

    if (GEN) {
        cplx A = make_float2(1.f, 0.f);
#pragma unroll
        for (int j = 0; j < 9; ++j) {
            int bit = (g >> (8 - j)) & 1;  // qubit j = g bit (8-j)
            int xb = x[b * 9 + j];
            A = cmul(A, g_Utab[j * 4 + bit * 2 + xb]);
        }
#pragma unroll
        for (int t = 0; t < 8; ++t) T[t] = cmul(T[t], A);
    }

    const cplx* UL = g_Utab + layer * NQ * 4;
    gate_inreg(T, 1, GQ(17));   // index bit 0
    gate_inreg(T, 2, GQ(16));   // index bit 1
    gate_inreg(T, 4, GQ(15));   // index bit 2
    gate_shfl(T, 1,  lane & 1,  GQ(14));  // index bit 3
    gate_shfl(T, 2,  lane & 2,  GQ(13));
    gate_shfl(T, 4,  lane & 4,  GQ(12));
    gate_shfl(T, 8,  lane & 8,  GQ(11));
    gate_shfl(T, 16, lane & 16, GQ(10));
    gate_shfl(T, 32, lane & 32, GQ(9));   // index bit 8

    float4* ld = (float4*)(dst + (((size_t)b << 18) | (size_t)(h << 9)) + lane * 8);
    ld[0] = make_float4(T[0].x, T[0].y, T[1].x, T[1].y);
    ld[1] = make_float4(T[2].x, T[2].y, T[3].x, T[3].y);
    ld[2] = make_float4(T[4].x, T[4].y, T[5].x, T[5].y);
    ld[3] = make_float4(T[6].x, T[6].y, T[7].x, T[7].y);
}

// ------------------------------------------------------------ phase B -------
// In-place. Block: batch b, 16 columns (low-bit values), all 512 rows.
// 1024 threads: stage-in/out tid pair (2m,2m+1) covers one full 128-B line of
// a row -> no partial-line fetch/write. LDS tile col-major, 16B-unit XOR
// swizzle (u' = u ^ ((u>>3)&7)) -> even bank distribution on all accesses.
// Wave wv (0..15) owns column wv: 8 rows/lane in registers.
// FINAL: instead of writing back, fold final Gray perm + measurement:
//   index bits 17..14 = lane bits 5..2 -> signs are per-lane constants.
template <int FINAL>
__global__ __launch_bounds__(1024) void k_phaseB(int sel, int layer,
                                                 float* __restrict__ out) {
    cplx* __restrict__ state = g_S[sel];
    __shared__ cplx tile[16 * 512];  // 64 KiB
    __shared__ float facc[16][4];
    const int tid = threadIdx.x;
    const int lane = tid & 63;
    const int wv = tid >> 6;                 // 0..15
    const int b = blockIdx.x >> 5;
    const int cb = blockIdx.x & 31;          // column block (16 cols)
    cplx* gbase = state + (((size_t)b << 18) | (size_t)(cb * 16));

    {   // stage in: r = tid>>1, half = tid&1 -> 8 cols (64 B); pair = full line
        const int r = tid >> 1, half = tid & 1;
        const float4* gs = (const float4*)(gbase + ((size_t)r << 9) + half * 8);
        float4 a0 = gs[0], a1 = gs[1], a2 = gs[2], a3 = gs[3];
        cplx w8[8] = { {a0.x,a0.y},{a0.z,a0.w},{a1.x,a1.y},{a1.z,a1.w},
                       {a2.x,a2.y},{a2.z,a2.w},{a3.x,a3.y},{a3.z,a3.w} };
        int u = r >> 1;
        int us = u ^ ((u >> 3) & 7);
        int basep = us * 2 + (r & 1);
#pragma unroll
        for (int k = 0; k < 8; ++k) tile[(half * 8 + k) * 512 + basep] = w8[k];
    }
    __syncthreads();

    cplx T[8];  // rows lane*8 .. lane*8+7 of column wv
#pragma unroll
    for (int j = 0; j < 4; ++j) {
        int u = lane * 4 + j;
        int us = u ^ ((u >> 3) & 7);
        float4 q = *(const float4*)&tile[wv * 512 + us * 2];
        T[2 * j]     = make_float2(q.x, q.y);
        T[2 * j + 1] = make_float2(q.z, q.w);
    }

    const cplx* UL = g_Utab + layer * NQ * 4;
    gate_inreg(T, 1, GQ(8));    // index bit 9
    gate_inreg(T, 2, GQ(7));
    gate_inreg(T, 4, GQ(6));
    gate_shfl(T, 1,  lane & 1,  GQ(5));  // index bit 12
    gate_shfl(T, 2,  lane & 2,  GQ(4));
    gate_shfl(T, 4,  lane & 4,  GQ(3));
    gate_shfl(T, 8,  lane & 8,  GQ(2));
    gate_shfl(T, 16, lane & 16, GQ(1));
    gate_shfl(T, 32, lane & 32, GQ(0));  // index bit 17

    if (FINAL) {
        float s = 0.f;
#pragma unroll
        for (int t = 0; t < 8; ++t)
            s = fmaf(T[t].x, T[t].x, fmaf(T[t].y, T[t].y, s));
        // final perm: o = invGray(m); sign bits = prefix parity of m bits 17..14
        int l5 = (lane >> 5) & 1, l4 = (lane >> 4) & 1;
        int l3 = (lane >> 3) & 1, l2 = (lane >> 2) & 1;
        int o17 = l5, o16 = o17 ^ l4, o15 = o16 ^ l3, o14 = o15 ^ l2;
        float e0 = o17 ? -s : s, e1 = o16 ? -s : s;
        float e2 = o15 ? -s : s, e3 = o14 ? -s : s;
#pragma unroll
        for (int off = 32; off >= 1; off >>= 1) {
            e0 += __shfl_xor(e0, off); e1 += __shfl_xor(e1, off);
            e2 += __shfl_xor(e2, off); e3 += __shfl_xor(e3, off);
        }
        if (lane == 0) {
            facc[wv][0] = e0; facc[wv][1] = e1;
            facc[wv][2] = e2; facc[wv][3] = e3;
        }
        __syncthreads();
        if (tid < 4) {
            float tot = 0.f;
#pragma unroll
            for (int k = 0; k < 16; ++k) tot += facc[k][tid];
            atomicAdd(&out[b * 4 + tid], tot);
        }
        return;
    }

#pragma unroll
    for (int j = 0; j < 4; ++j) {   // write back own column (no cross-wave hazard)
        int u = lane * 4 + j;
        int us = u ^ ((u >> 3) & 7);
        *(float4*)&tile[wv * 512 + us * 2] =
            make_float4(T[2 * j].x, T[2 * j].y, T[2 * j + 1].x, T[2 * j + 1].y);
    }
    __syncthreads();

    {   // stage out
        const int r = tid >> 1, half = tid & 1;
        int u = r >> 1;
        int us = u ^ ((u >> 3) & 7);
        int basep = us * 2 + (r & 1);
        cplx o[8];
#pragma unroll
        for (int k = 0; k < 8; ++k) o[k] = tile[(half * 8 + k) * 512 + basep];
        float4* gd = (float4*)(gbase + ((size_t)r << 9) + half * 8);
        gd[0] = make_float4(o[0].x, o[0].y, o[1].x, o[1].y);
        gd[1] = make_float4(o[2].x, o[2].y, o[3].x, o[3].y);
        gd[2] = make_float4(o[4].x, o[4].y, o[5].x, o[5].y);
        gd[3] = make_float4(o[6].x, o[6].y, o[7].x, o[7].y);
    }
}

// ------------------------------------------------------------- launch -------
extern "C" void kernel_launch(void* const* d_in, const int* in_sizes, int n_in,
                              void* d_out, int out_size, void* d_ws, size_t ws_size,
                              hipStream_t stream) {
    const float* w = (const float*)d_in[0];   // (4,18,3) f32
    const int* x = (const int*)d_in[1];       // (64,9) i32
    float* out = (float*)d_out;               // (64,4) f32
    (void)d_ws; (void)ws_size; (void)n_in; (void)in_sizes;

    hipMemsetAsync(d_out, 0, (size_t)out_size * sizeof(float), stream);
    k_prep<<<1, 512, 0, stream>>>(w);
    // layer 0 (A*B outer product) + perm + layer-1 low gates -> S0
    k_phaseA<1><<<8192, 256, 0, stream>>>(0, 0, x, 1);
    k_phaseB<0><<<2048, 1024, 0, stream>>>(0, 1, nullptr);  // layer-1 high gates
    k_phaseA<0><<<8192, 256, 0, stream>>>(0, 1, x, 2);
    k_phaseB<0><<<2048, 1024, 0, stream>>>(1, 2, nullptr);
    k_phaseA<0><<<8192, 256, 0, stream>>>(1, 0, x, 3);
    // layer-3 high gates + final perm + measurement (no writeback)
    k_phaseB<1><<<2048, 1024, 0, stream>>>(0, 3, out);
}